// Round 22
// baseline (1252.617 us; speedup 1.0000x reference)
//
#include <hip/hip_runtime.h>
#include <hip/hip_bf16.h>
#include <math.h>

#define B_ 512
#define E_ 256
#define H_ 512
#define V_ 4096
#define T_ 18
#define L_ 20
#define MARGIN_ 0.04f
#define CCAP_ 64

typedef __attribute__((ext_vector_type(8))) short bf16x8;
typedef __attribute__((ext_vector_type(4))) float f32x4;

__device__ __forceinline__ unsigned short bfbits(float x) {
  __hip_bfloat16 b = __float2bfloat16(x);
  return *reinterpret_cast<unsigned short*>(&b);
}
__device__ __forceinline__ float bf2f(unsigned short u) {
  unsigned v = ((unsigned)u) << 16;
  return *reinterpret_cast<float*>(&v);
}
// exact 3-way bf16 split: x ~= s1 + s2 + s3, residuals exact in fp32
__device__ __forceinline__ void split3(float x, unsigned short& s1,
                                       unsigned short& s2, unsigned short& s3) {
  s1 = bfbits(x);
  float r = x - bf2f(s1);
  s2 = bfbits(r);
  float r2 = r - bf2f(s2);
  s3 = bfbits(r2);
}

// ==== prep: cat fp32 + WoutB bf16 + Whh 3-way bf16 split (float4-vect) ====
__global__ __launch_bounds__(256) void kprep32(const float* __restrict__ pa,
                                               const float* __restrict__ pb,
                                               const float* __restrict__ Wout,
                                               const float* __restrict__ Whh,
                                               float* __restrict__ cat,
                                               __hip_bfloat16* __restrict__ WB,
                                               unsigned short* __restrict__ W1,
                                               unsigned short* __restrict__ W2,
                                               unsigned short* __restrict__ W3) {
  int idx = blockIdx.x * 256 + threadIdx.x;      // < 851968 quads
  if (idx < 131072) {
    int e0 = idx * 4;
    int b = e0 >> 10, k = e0 & 1023;
    float4 v = (k < 512) ? *reinterpret_cast<const float4*>(pa + (size_t)b * 512 + k)
                         : *reinterpret_cast<const float4*>(pb + (size_t)b * 512 + (k - 512));
    *reinterpret_cast<float4*>(cat + e0) = v;
  } else if (idx < 655360) {
    int e0 = (idx - 131072) * 4;                 // < 2097152
    float4 w = *reinterpret_cast<const float4*>(Wout + e0);
    ushort4 o;
    o.x = bfbits(w.x); o.y = bfbits(w.y); o.z = bfbits(w.z); o.w = bfbits(w.w);
    *reinterpret_cast<ushort4*>(WB + e0) = o;
  } else if (idx < 851968) {
    int e0 = (idx - 655360) * 4;                 // < 786432
    float4 w = *reinterpret_cast<const float4*>(Whh + e0);
    ushort4 o1, o2, o3;
    split3(w.x, o1.x, o2.x, o3.x);
    split3(w.y, o1.y, o2.y, o3.y);
    split3(w.z, o1.z, o2.z, o3.z);
    split3(w.w, o1.w, o2.w, o3.w);
    *reinterpret_cast<ushort4*>(W1 + e0) = o1;
    *reinterpret_cast<ushort4*>(W2 + e0) = o2;
    *reinterpret_cast<ushort4*>(W3 + e0) = o3;
  }
}

// ===== fp32 GEMM body, 128x64 tile, 8x4/thread, split-K (setup only) =====
__device__ __forceinline__ void gemm64_body(const float* __restrict__ A,
                                            const float* __restrict__ W,
                                            float* __restrict__ P,
                                            int N, int lda, int kPer,
                                            int bx, int by, int bz, int My,
                                            int tid, char* smemRaw) {
  float (*As)[130] = reinterpret_cast<float(*)[130]>(smemRaw);
  float (*Bs)[68]  = reinterpret_cast<float(*)[68]>(smemRaw + 8320);
  const int tx = tid & 15, ty = tid >> 4;
  const int bn = bx * 64, bm = by * 128;
  const int k0 = bz * kPer;
  const size_t pOff = (size_t)bz * My * 128 * N;
  const int kk0 = tid & 15;
  const int ra0 = (tid >> 4) * 8;
  const int cb0 = (tid >> 4) * 4;

  float acc[8][4] = {};
  for (int kb = 0; kb < kPer; kb += 16) {
#pragma unroll
    for (int q = 0; q < 8; ++q)
      As[kk0][ra0 + q] = A[(size_t)(bm + ra0 + q) * lda + k0 + kb + kk0];
#pragma unroll
    for (int q = 0; q < 4; ++q)
      Bs[kk0][cb0 + q] = W[(size_t)(bn + cb0 + q) * lda + k0 + kb + kk0];
    __syncthreads();
#pragma unroll
    for (int kk = 0; kk < 16; ++kk) {
      float a[8], b[4];
#pragma unroll
      for (int i = 0; i < 8; ++i) a[i] = As[kk][ty + 16 * i];
#pragma unroll
      for (int j = 0; j < 4; ++j) b[j] = Bs[kk][tx + 16 * j];
#pragma unroll
      for (int i = 0; i < 8; ++i)
#pragma unroll
        for (int j = 0; j < 4; ++j) acc[i][j] = fmaf(a[i], b[j], acc[i][j]);
    }
    __syncthreads();
  }
#pragma unroll
  for (int i = 0; i < 8; ++i) {
    size_t r = (size_t)(bm + ty + 16 * i);
#pragma unroll
    for (int j = 0; j < 4; ++j)
      P[pOff + r * N + bn + tx + 16 * j] = acc[i][j];
  }
}

// ===== setup: h0P gemm (256 blk) + giP gemm (768 blk) in one launch =====
__global__ __launch_bounds__(256) void setupGemms(const float* __restrict__ cat,
                                                  const float* __restrict__ Winit,
                                                  float* __restrict__ h0P,
                                                  const float* __restrict__ emb,
                                                  const float* __restrict__ Wih,
                                                  float* __restrict__ giP) {
  __shared__ __align__(16) char smemRaw[12672];
  const int bid = blockIdx.x, tid = threadIdx.x;
  if (bid < 256) {
    int bx = bid & 7, by = (bid >> 3) & 3, bz = bid >> 5;
    gemm64_body(cat, Winit, h0P, 512, 1024, 128, bx, by, bz, 4, tid, smemRaw);
  } else {
    int gid = bid - 256;
    int bx = gid % 24, by = gid / 24;
    gemm64_body(emb, Wih, giP, 1536, 256, 256, bx, by, 0, 32, tid, smemRaw);
  }
}

// ==== h0 = sum of 8 partials + b_init (fp64); fp32 + 3-way bf16 split out ===
__global__ __launch_bounds__(256) void reduceH0(const float* __restrict__ parts,
                                                const float* __restrict__ binit,
                                                float* __restrict__ h,
                                                unsigned short* __restrict__ h1,
                                                unsigned short* __restrict__ h2,
                                                unsigned short* __restrict__ h3) {
  int i = blockIdx.x * 256 + threadIdx.x;
  double s = (double)binit[i & 511];
#pragma unroll
  for (int c = 0; c < 8; ++c) s += (double)parts[(size_t)c * 262144 + i];
  float f = (float)s;
  h[i] = f;
  split3(f, h1[i], h2[i], h3[i]);
}

// ====== gh via bf16x3 MFMA: ghF[512,1536] = h @ Whh^T (fp32-grade) ======
// 6 product passes accumulated into one fp32 MFMA accumulator; K=512 in-reg.
__device__ __forceinline__ void gh_mfma_body(const unsigned short* __restrict__ h1,
                                             const unsigned short* __restrict__ h2,
                                             const unsigned short* __restrict__ h3,
                                             const unsigned short* __restrict__ W1,
                                             const unsigned short* __restrict__ W2,
                                             const unsigned short* __restrict__ W3,
                                             float* __restrict__ ghF,
                                             int bid, int tid) {
  const int wave = tid >> 6, lane = tid & 63;
  const int bx = bid % 24, by = bid / 24;          // 24 col-tiles x 8 row-grps
  const int bm = by * 64 + wave * 16;
  const int bn = bx * 64;
  const int rA = lane & 15, g = lane >> 4;
  const size_t aoff = (size_t)(bm + rA) * H_ + g * 8;
  const size_t boff = (size_t)(bn + rA) * H_ + g * 8;
  f32x4 acc[4] = {};
  for (int k0 = 0; k0 < H_; k0 += 32) {
    bf16x8 a1 = *reinterpret_cast<const bf16x8*>(h1 + aoff + k0);
    bf16x8 a2 = *reinterpret_cast<const bf16x8*>(h2 + aoff + k0);
    bf16x8 a3 = *reinterpret_cast<const bf16x8*>(h3 + aoff + k0);
#pragma unroll
    for (int j = 0; j < 4; ++j) {
      size_t bo = boff + (size_t)j * 16 * H_ + k0;
      bf16x8 b1 = *reinterpret_cast<const bf16x8*>(W1 + bo);
      bf16x8 b2 = *reinterpret_cast<const bf16x8*>(W2 + bo);
      bf16x8 b3 = *reinterpret_cast<const bf16x8*>(W3 + bo);
      acc[j] = __builtin_amdgcn_mfma_f32_16x16x32_bf16(a1, b1, acc[j], 0, 0, 0);
      acc[j] = __builtin_amdgcn_mfma_f32_16x16x32_bf16(a1, b2, acc[j], 0, 0, 0);
      acc[j] = __builtin_amdgcn_mfma_f32_16x16x32_bf16(a2, b1, acc[j], 0, 0, 0);
      acc[j] = __builtin_amdgcn_mfma_f32_16x16x32_bf16(a1, b3, acc[j], 0, 0, 0);
      acc[j] = __builtin_amdgcn_mfma_f32_16x16x32_bf16(a2, b2, acc[j], 0, 0, 0);
      acc[j] = __builtin_amdgcn_mfma_f32_16x16x32_bf16(a3, b1, acc[j], 0, 0, 0);
    }
  }
#pragma unroll
  for (int j = 0; j < 4; ++j)
#pragma unroll
    for (int r = 0; r < 4; ++r)
      ghF[(size_t)(bm + g * 4 + r) * 1536 + bn + j * 16 + rA] = acc[j][r];
}

// ====== screen: bf16 MFMA -> raw logits to loP (R19/R21-proven) ======
__device__ __forceinline__ void screen_body(const unsigned short* __restrict__ hB,
                                            const __hip_bfloat16* __restrict__ WoutB,
                                            float* __restrict__ loP,
                                            int bid, int tid) {
  const int wave = tid >> 6, lane = tid & 63;
  const int bx = bid & 63, by = bid >> 6;
  const int bm = by * 64 + wave * 16;
  const int bn = bx * 64;
  const int rA = lane & 15, g = lane >> 4;
  const unsigned short* ha = hB + (size_t)(bm + rA) * H_ + g * 8;
  const __hip_bfloat16* wb = WoutB + (size_t)(bn + rA) * H_ + g * 8;
  f32x4 acc[4] = {};
  for (int k0 = 0; k0 < H_; k0 += 32) {
    bf16x8 a = *reinterpret_cast<const bf16x8*>(ha + k0);
#pragma unroll
    for (int j = 0; j < 4; ++j) {
      bf16x8 b = *reinterpret_cast<const bf16x8*>(wb + (size_t)j * 16 * H_ + k0);
      acc[j] = __builtin_amdgcn_mfma_f32_16x16x32_bf16(a, b, acc[j], 0, 0, 0);
    }
  }
#pragma unroll
  for (int j = 0; j < 4; ++j)
#pragma unroll
    for (int r = 0; r < 4; ++r)
      loP[(size_t)(bm + g * 4 + r) * V_ + bn + j * 16 + rA] = acc[j][r];
}

// ====== pick: wave-shfl reductions (R19/R21-proven, unchanged) ======
__device__ __forceinline__ int pick_body(const float* __restrict__ loP,
                                         const float* __restrict__ h,
                                         const float* __restrict__ Wout,
                                         const float* __restrict__ bout,
                                         const float* __restrict__ ub,
                                         int bid, int tid, char* smemRaw) {
  double* sd    = reinterpret_cast<double*>(smemRaw);
  int*    pre   = reinterpret_cast<int*>(smemRaw + 2048);
  int*    candV = reinterpret_cast<int*>(smemRaw + 3072);
  float*  swv   = reinterpret_cast<float*>(smemRaw + 3328);
  int*    swi   = reinterpret_cast<int*>(smemRaw + 3344);
  int*    sct   = reinterpret_cast<int*>(smemRaw + 3360);
  double* bestS = reinterpret_cast<double*>(smemRaw + 3376);
  int*    bestV = reinterpret_cast<int*>(smemRaw + 3384);
  const int lane = tid & 63, wv = tid >> 6;
  const float* l0 = loP + (size_t)bid * V_;
  float sloc[16];
  float best = -1e30f; int bi = 0x7fffffff;
#pragma unroll
  for (int i = 0; i < 16; ++i) {
    int v = tid + 256 * i;
    float s = l0[v] + bout[v] - logf(-logf(ub[v]));
    sloc[i] = s;
    if (s > best) { best = s; bi = v; }
  }
#pragma unroll
  for (int off = 1; off < 64; off <<= 1) {
    float ov = __shfl_xor(best, off, 64);
    int   oi = __shfl_xor(bi,  off, 64);
    if (ov > best || (ov == best && oi < bi)) { best = ov; bi = oi; }
  }
  if (lane == 0) { swv[wv] = best; swi[wv] = bi; }
  __syncthreads();
  float smax = swv[0]; int amax = swi[0];
#pragma unroll
  for (int w = 1; w < 4; ++w) {
    float ov = swv[w]; int oi = swi[w];
    if (ov > smax || (ov == smax && oi < amax)) { smax = ov; amax = oi; }
  }
  int c = 0;
#pragma unroll
  for (int i = 0; i < 16; ++i) if (sloc[i] >= smax - MARGIN_) ++c;
  int csum = c;
#pragma unroll
  for (int off = 1; off < 64; off <<= 1) csum += __shfl_xor(csum, off, 64);
  if (lane == 0) sct[wv] = csum;
  __syncthreads();
  int tot = sct[0] + sct[1] + sct[2] + sct[3];

  int tok;
  if (tot == 1) {
    tok = amax;
  } else if (tot <= CCAP_) {
    int lv[16];
    int cc = 0;
#pragma unroll
    for (int i = 0; i < 16; ++i)
      if (sloc[i] >= smax - MARGIN_) { if (cc < 16) lv[cc] = tid + 256 * i; ++cc; }
    pre[tid] = cc;
    __syncthreads();
    for (int off = 1; off < 256; off <<= 1) {
      int vv = (tid >= off) ? pre[tid - off] : 0;
      __syncthreads();
      pre[tid] += vv;
      __syncthreads();
    }
    int base = pre[tid] - cc;
    for (int q = 0; q < cc; ++q) candV[base + q] = lv[q];
    if (tid == 0) { *bestS = -1e300; *bestV = 0x7fffffff; }
    __syncthreads();
    const float* hb = h + (size_t)bid * H_;
    for (int ci = 0; ci < tot; ++ci) {
      int v = candV[ci];
      const float* wr = Wout + (size_t)v * H_;
      double p = (double)hb[tid] * (double)wr[tid]
               + (double)hb[tid + 256] * (double)wr[tid + 256];
#pragma unroll
      for (int off = 1; off < 64; off <<= 1) p += __shfl_xor(p, off, 64);
      if (lane == 0) sd[wv] = p;
      __syncthreads();
      if (tid == 0) {
        double s = sd[0] + sd[1] + sd[2] + sd[3]
                 + (double)bout[v] - log(-log((double)ub[v]));
        if (s > *bestS || (s == *bestS && v < *bestV)) { *bestS = s; *bestV = v; }
      }
      __syncthreads();
    }
    tok = *bestV;
  } else {
    const float* hb = h + (size_t)bid * H_;
    double dbest = -1e300; int dbi = 0x7fffffff;
    for (int i = 0; i < 16; ++i) {
      int v = tid + 256 * i;
      const float* wr = Wout + (size_t)v * H_;
      double dot = 0.0;
      for (int k = 0; k < H_; ++k) dot = fma((double)hb[k], (double)wr[k], dot);
      double s = dot + (double)bout[v] - log(-log((double)ub[v]));
      if (s > dbest) { dbest = s; dbi = v; }
    }
#pragma unroll
    for (int off = 1; off < 64; off <<= 1) {
      double od = __shfl_xor(dbest, off, 64);
      int    oi = __shfl_xor(dbi,  off, 64);
      if (od > dbest || (od == dbest && oi < dbi)) { dbest = od; dbi = oi; }
    }
    if (lane == 0) { sd[wv] = dbest; pre[wv] = dbi; }
    __syncthreads();
    double bs = sd[0]; int bv = pre[0];
#pragma unroll
    for (int w = 1; w < 4; ++w) {
      if (sd[w] > bs || (sd[w] == bs && pre[w] < bv)) { bs = sd[w]; bv = pre[w]; }
    }
    tok = bv;
  }
  return tok;
}

// ===== gates core: single ghF read (no partials), fp32; 3-way split out =====
__device__ __forceinline__ void gates_one(const float* __restrict__ ghF,
                                          const float* __restrict__ g0,
                                          const float* __restrict__ bih,
                                          const float* __restrict__ bhh,
                                          float* __restrict__ h,
                                          unsigned short* __restrict__ h1,
                                          unsigned short* __restrict__ h2,
                                          unsigned short* __restrict__ h3,
                                          int bid, int j) {
  size_t base = (size_t)bid * 1536;
  int idx = bid * 512 + j;
  float gr = ghF[base + j]        + bhh[j];
  float gz = ghF[base + 512 + j]  + bhh[512 + j];
  float gn = ghF[base + 1024 + j] + bhh[1024 + j];
  float ir  = g0[j]        + bih[j];
  float iz  = g0[512 + j]  + bih[512 + j];
  float inn = g0[1024 + j] + bih[1024 + j];
  float r = 1.f / (1.f + expf(-(ir + gr)));
  float z = 1.f / (1.f + expf(-(iz + gz)));
  float n = tanhf(inn + r * gn);
  float hn = (1.f - z) * n + z * h[idx];
  h[idx] = hn;
  split3(hn, h1[idx], h2[idx], h3[idx]);
}

// ===== K0: standalone gates (initial step, tok = SOS) =====
__global__ __launch_bounds__(256) void gates_init(const float* __restrict__ ghF,
                                                  const float* __restrict__ giP,
                                                  const float* __restrict__ bih,
                                                  const float* __restrict__ bhh,
                                                  float* __restrict__ h,
                                                  unsigned short* __restrict__ h1,
                                                  unsigned short* __restrict__ h2,
                                                  unsigned short* __restrict__ h3) {
  const int bid = blockIdx.x, tid = threadIdx.x;
  const float* g0 = giP + (size_t)1 * 1536;
  gates_one(ghF, g0, bih, bhh, h, h1, h2, h3, bid, tid);
  gates_one(ghF, g0, bih, bhh, h, h1, h2, h3, bid, 256 + tid);
}

// ===== K1: gh bf16x3 MFMA (blocks 0..191) + screen (192..703) =====
__global__ __launch_bounds__(256) void fusedA(const unsigned short* __restrict__ h1,
                                              const unsigned short* __restrict__ h2,
                                              const unsigned short* __restrict__ h3,
                                              const unsigned short* __restrict__ W1,
                                              const unsigned short* __restrict__ W2,
                                              const unsigned short* __restrict__ W3,
                                              const __hip_bfloat16* __restrict__ WoutB,
                                              float* __restrict__ ghF,
                                              float* __restrict__ loP,
                                              int doGemm) {
  const int bid = blockIdx.x, tid = threadIdx.x;
  if (bid < 192) {
    if (doGemm) gh_mfma_body(h1, h2, h3, W1, W2, W3, ghF, bid, tid);
  } else {
    screen_body(h1, WoutB, loP, bid - 192, tid);
  }
}

// ===== K2: hoisted ghF loads -> pick tok(t) -> gates(t+1) =====
__global__ __launch_bounds__(256) void fusedB(const float* __restrict__ loP,
                                              float* __restrict__ h,
                                              const float* __restrict__ Wout,
                                              const float* __restrict__ bout,
                                              const float* __restrict__ u,
                                              const float* __restrict__ ghF,
                                              const float* __restrict__ giP,
                                              const float* __restrict__ bih,
                                              const float* __restrict__ bhh,
                                              unsigned short* __restrict__ h1,
                                              unsigned short* __restrict__ h2,
                                              unsigned short* __restrict__ h3,
                                              int* __restrict__ toks,
                                              int t, int doGates) {
  __shared__ __align__(16) char smemRaw[5440];
  const int bid = blockIdx.x, tid = threadIdx.x;
  const float* ub = u + (size_t)bid * V_;
  int tok = pick_body(loP, h, Wout, bout, ub, bid, tid, smemRaw);
  if (tid == 0) toks[t * B_ + bid] = tok;
  if (doGates) {
    const float* g0 = giP + (size_t)tok * 1536;
    gates_one(ghF, g0, bih, bhh, h, h1, h2, h3, bid, tid);
    gates_one(ghF, g0, bih, bhh, h, h1, h2, h3, bid, 256 + tid);
  }
}

// ============== final: zero + one-hot scatter + SOS/EOS, fp32 ==============
__global__ __launch_bounds__(256) void kfinal32(float* __restrict__ out,
                                                const int* __restrict__ toks) {
  size_t c = (size_t)blockIdx.x * 256 + threadIdx.x;
  size_t e0 = c * 4;
  int v0 = (int)(e0 & (size_t)(V_ - 1));
  size_t row = e0 >> 12;
  int p = (int)(row % L_);
  int b = (int)(row / L_);
  int tok;
  if (p == 0)           tok = 1;
  else if (p == L_ - 1) tok = 2;
  else                  tok = toks[(p - 1) * B_ + b];
  float4 val = make_float4(0.f, 0.f, 0.f, 0.f);
  int d = tok - v0;
  if (d >= 0 && d < 4) {
    if (d == 0) val.x = 1.f; else if (d == 1) val.y = 1.f;
    else if (d == 2) val.z = 1.f; else val.w = 1.f;
  }
  reinterpret_cast<float4*>(out)[c] = val;
}

// ---------------- environment markers ----------------
__global__ void kmark_ws(float* out) {
  if (threadIdx.x == 0) out[0] = 16.0f;
}
__global__ void kmark_resolver(float* out) {
  if (threadIdx.x == 0) out[2] = 11.0f;
}

// ================================ launch ================================
extern "C" void kernel_launch(void* const* d_in, const int* in_sizes, int n_in,
                              void* d_out, int out_size, void* d_ws, size_t ws_size,
                              hipStream_t stream) {
  static const int EXPECT[12] = {262144, 262144, 524288, 512, 393216, 786432,
                                 1536, 1536, 2097152, 4096, 1048576, 37748736};
  const float* R[12];
  bool resolved = (n_in == 12);
  if (resolved) {
    bool used[12] = {};
    for (int i = 0; i < 12; ++i) {
      int f = -1;
      for (int j = 0; j < 12; ++j)
        if (!used[j] && in_sizes[j] == EXPECT[i]) { f = j; break; }
      if (f < 0) { resolved = false; break; }
      used[f] = true;
      R[i] = (const float*)d_in[f];
    }
  }
  if (!resolved)
    for (int i = 0; i < 12 && i < n_in; ++i) R[i] = (const float*)d_in[i];

  const float *pa = R[0], *pb = R[1], *Winit = R[2], *binit = R[3],
              *Wih = R[4], *Whh = R[5], *bih = R[6], *bhh = R[7],
              *Wout = R[8], *bout = R[9], *emb = R[10], *ug = R[11];
  float* out = (float*)d_out;

  const size_t TOK_BYTES = (size_t)T_ * B_ * sizeof(int);   // 36864
  if (ws_size < TOK_BYTES) { kmark_ws<<<1, 64, 0, stream>>>(out); return; }
  int* toks = (int*)d_ws;

  // scratch (fp32-equiv floats, total 12,058,624 = 48.2 MB):
  //  h | giP | ghF(aliases cat pre-loop) | loP(aliases h0P pre-loop)
  //  | hB1..3 | WoutB | W1..3
  const size_t SC_FLOATS = 12058624;
  float* sc;
  if (ws_size >= 40960 + SC_FLOATS * sizeof(float)) {
    sc = (float*)((char*)d_ws + 40960);
  } else {
    sc = (float*)d_out;   // head of 167.8 MB out; kfinal32 rebuilds last
  }
  float* h    = sc;                                     // 262,144
  float* giP  = sc + 262144;                            // 6,291,456
  float* ghF  = sc + 6553600;                           // 786,432 (512x1536)
  float* loP  = sc + 7340032;                           // 2,097,152
  unsigned short* hB1 = (unsigned short*)(sc + 9437184);   // 262,144 bf16
  unsigned short* hB2 = (unsigned short*)(sc + 9568256);
  unsigned short* hB3 = (unsigned short*)(sc + 9699328);
  __hip_bfloat16* WoutB = (__hip_bfloat16*)(sc + 9830400); // 2,097,152 bf16
  unsigned short* W1  = (unsigned short*)(sc + 10878976);  // 786,432 bf16
  unsigned short* W2  = (unsigned short*)(sc + 11272192);
  unsigned short* W3  = (unsigned short*)(sc + 11665408);
  float* cat  = ghF;                                    // 524,288 (pre-loop)
  float* h0P  = loP;                                    // 8 x 262,144 (pre-loop)

  // ---- setup ----
  kprep32<<<3328, 256, 0, stream>>>(pa, pb, Wout, Whh, cat, WoutB, W1, W2, W3);
  setupGemms<<<1024, 256, 0, stream>>>(cat, Winit, h0P, emb, Wih, giP);
  reduceH0<<<1024, 256, 0, stream>>>(h0P, binit, h, hB1, hB2, hB3);
  // gh(h_0) via MFMA, then gates(SOS) -> h_1
  fusedA<<<192, 256, 0, stream>>>(hB1, hB2, hB3, W1, W2, W3, WoutB, ghF, loP, 1);
  gates_init<<<512, 256, 0, stream>>>(ghF, giP, bih, bhh, h, hB1, hB2, hB3);

  // ---- decode loop: 2 launches per step ----
  for (int t = 0; t < T_; ++t) {
    const float* uslice = ug + (size_t)t * B_ * V_;
    int notLast = (t < T_ - 1) ? 1 : 0;
    // gh(h_{t+1}) -> ghF (blocks 0..191); screen(h_{t+1}) -> loP_t (192..703)
    fusedA<<<704, 256, 0, stream>>>(hB1, hB2, hB3, W1, W2, W3, WoutB,
                                    ghF, loP, notLast);
    // pick tok_t ; gates -> h_{t+2}
    fusedB<<<512, 256, 0, stream>>>(loP, h, Wout, bout, uslice, ghF, giP,
                                    bih, bhh, hB1, hB2, hB3, toks, t, notLast);
  }

  // ---- assemble fp32 output ----
  kfinal32<<<40960, 256, 0, stream>>>(out, toks);
  if (!resolved) kmark_resolver<<<1, 64, 0, stream>>>(out);
}

// Round 23
// 1041.662 us; speedup vs baseline: 1.2025x; 1.2025x over previous
//
#include <hip/hip_runtime.h>
#include <hip/hip_bf16.h>
#include <math.h>

#define B_ 512
#define E_ 256
#define H_ 512
#define V_ 4096
#define T_ 18
#define L_ 20
#define MARGIN_ 0.04f
#define CCAP_ 64

typedef __attribute__((ext_vector_type(8))) short bf16x8;
typedef __attribute__((ext_vector_type(4))) float f32x4;

// ========== prep: cat fp32 + WoutB bf16 (float4-vectorized) ==========
__global__ __launch_bounds__(256) void kprep32(const float* __restrict__ pa,
                                               const float* __restrict__ pb,
                                               const float* __restrict__ Wout,
                                               float* __restrict__ cat,
                                               __hip_bfloat16* __restrict__ WB) {
  int idx = blockIdx.x * 256 + threadIdx.x;      // < 655360 quads
  if (idx < 131072) {
    int e0 = idx * 4;
    int b = e0 >> 10, k = e0 & 1023;             // quads never straddle 512
    float4 v = (k < 512) ? *reinterpret_cast<const float4*>(pa + (size_t)b * 512 + k)
                         : *reinterpret_cast<const float4*>(pb + (size_t)b * 512 + (k - 512));
    *reinterpret_cast<float4*>(cat + e0) = v;
  } else {
    int e0 = (idx - 131072) * 4;                 // < 2097152
    float4 w = *reinterpret_cast<const float4*>(Wout + e0);
    __hip_bfloat16 b0 = __float2bfloat16(w.x), b1 = __float2bfloat16(w.y);
    __hip_bfloat16 b2 = __float2bfloat16(w.z), b3 = __float2bfloat16(w.w);
    ushort4 o;
    o.x = *reinterpret_cast<unsigned short*>(&b0);
    o.y = *reinterpret_cast<unsigned short*>(&b1);
    o.z = *reinterpret_cast<unsigned short*>(&b2);
    o.w = *reinterpret_cast<unsigned short*>(&b3);
    *reinterpret_cast<ushort4*>(WB + e0) = o;
  }
}

// ===== fp32 GEMM body, 128x64 tile (MxN), 8x4/thread, split-K (proven) =====
__device__ __forceinline__ void gemm64_body(const float* __restrict__ A,
                                            const float* __restrict__ W,
                                            float* __restrict__ P,
                                            int N, int lda, int kPer,
                                            int bx, int by, int bz, int My,
                                            int tid, char* smemRaw) {
  float (*As)[130] = reinterpret_cast<float(*)[130]>(smemRaw);          // 8320 B
  float (*Bs)[68]  = reinterpret_cast<float(*)[68]>(smemRaw + 8320);    // 4352 B
  const int tx = tid & 15, ty = tid >> 4;
  const int bn = bx * 64, bm = by * 128;
  const int k0 = bz * kPer;
  const size_t pOff = (size_t)bz * My * 128 * N;
  const int kk0 = tid & 15;
  const int ra0 = (tid >> 4) * 8;
  const int cb0 = (tid >> 4) * 4;

  float acc[8][4] = {};
  for (int kb = 0; kb < kPer; kb += 16) {
#pragma unroll
    for (int q = 0; q < 8; ++q)
      As[kk0][ra0 + q] = A[(size_t)(bm + ra0 + q) * lda + k0 + kb + kk0];
#pragma unroll
    for (int q = 0; q < 4; ++q)
      Bs[kk0][cb0 + q] = W[(size_t)(bn + cb0 + q) * lda + k0 + kb + kk0];
    __syncthreads();
#pragma unroll
    for (int kk = 0; kk < 16; ++kk) {
      float a[8], b[4];
#pragma unroll
      for (int i = 0; i < 8; ++i) a[i] = As[kk][ty + 16 * i];
#pragma unroll
      for (int j = 0; j < 4; ++j) b[j] = Bs[kk][tx + 16 * j];
#pragma unroll
      for (int i = 0; i < 8; ++i)
#pragma unroll
        for (int j = 0; j < 4; ++j) acc[i][j] = fmaf(a[i], b[j], acc[i][j]);
    }
    __syncthreads();
  }
#pragma unroll
  for (int i = 0; i < 8; ++i) {
    size_t r = (size_t)(bm + ty + 16 * i);
#pragma unroll
    for (int j = 0; j < 4; ++j)
      P[pOff + r * N + bn + tx + 16 * j] = acc[i][j];
  }
}

// ===== setup: h0P gemm (256 blk) + giP gemm (768 blk) in one launch =====
__global__ __launch_bounds__(256) void setupGemms(const float* __restrict__ cat,
                                                  const float* __restrict__ Winit,
                                                  float* __restrict__ h0P,
                                                  const float* __restrict__ emb,
                                                  const float* __restrict__ Wih,
                                                  float* __restrict__ giP) {
  __shared__ __align__(16) char smemRaw[12672];
  const int bid = blockIdx.x, tid = threadIdx.x;
  if (bid < 256) {
    // h0P: cat[512,1024] @ Winit[512,1024]^T, 128x64 tiles, split-K=8
    int bx = bid & 7, by = (bid >> 3) & 3, bz = bid >> 5;
    gemm64_body(cat, Winit, h0P, 512, 1024, 128, bx, by, bz, 4, tid, smemRaw);
  } else {
    // giP: emb[4096,256] @ Wih[1536,256]^T, 128x64 tiles, single chunk
    int gid = bid - 256;
    int bx = gid % 24, by = gid / 24;            // by in 0..31
    gemm64_body(emb, Wih, giP, 1536, 256, 256, bx, by, 0, 32, tid, smemRaw);
  }
}

// ===== standalone gh GEMM (setup step 0): split-K=4, 384 blocks =====
__global__ __launch_bounds__(256) void ghK(const float* __restrict__ h,
                                           const float* __restrict__ Whh,
                                           float* __restrict__ ghP) {
  __shared__ __align__(16) char smemRaw[12672];
  const int bid = blockIdx.x, tid = threadIdx.x;
  int bx = bid % 24, by = (bid / 24) & 3, bz = bid / 96;
  gemm64_body(h, Whh, ghP, 1536, 512, 128, bx, by, bz, 4, tid, smemRaw);
}

// ======== h0 = sum of 8 partials + b_init (fp64 sum); fp32 + bf16 out ======
__global__ __launch_bounds__(256) void reduceH0(const float* __restrict__ parts,
                                                const float* __restrict__ binit,
                                                float* __restrict__ h,
                                                __hip_bfloat16* __restrict__ hB) {
  int i = blockIdx.x * 256 + threadIdx.x;
  double s = (double)binit[i & 511];
#pragma unroll
  for (int c = 0; c < 8; ++c) s += (double)parts[(size_t)c * 262144 + i];
  float f = (float)s;
  h[i] = f;
  hB[i] = __float2bfloat16(f);
}

// ====== screen: bf16 MFMA -> raw logits to loP (proven) ======
__device__ __forceinline__ void screen_body(const __hip_bfloat16* __restrict__ hB,
                                            const __hip_bfloat16* __restrict__ WoutB,
                                            float* __restrict__ loP,
                                            int bid, int tid) {
  const int wave = tid >> 6, lane = tid & 63;
  const int bx = bid & 63, by = bid >> 6;
  const int bm = by * 64 + wave * 16;
  const int bn = bx * 64;
  const int rA = lane & 15, g = lane >> 4;
  const __hip_bfloat16* ha = hB + (size_t)(bm + rA) * H_ + g * 8;
  const __hip_bfloat16* wb = WoutB + (size_t)(bn + rA) * H_ + g * 8;
  f32x4 acc[4] = {};
  for (int k0 = 0; k0 < H_; k0 += 32) {
    bf16x8 a = *reinterpret_cast<const bf16x8*>(ha + k0);
#pragma unroll
    for (int j = 0; j < 4; ++j) {
      bf16x8 b = *reinterpret_cast<const bf16x8*>(wb + (size_t)j * 16 * H_ + k0);
      acc[j] = __builtin_amdgcn_mfma_f32_16x16x32_bf16(a, b, acc[j], 0, 0, 0);
    }
  }
#pragma unroll
  for (int j = 0; j < 4; ++j)
#pragma unroll
    for (int r = 0; r < 4; ++r)
      loP[(size_t)(bm + g * 4 + r) * V_ + bn + j * 16 + rA] = acc[j][r];
}

// ====== pick: wave-shfl reductions (proven) ======
__device__ __forceinline__ int pick_body(const float* __restrict__ loP,
                                         const float* __restrict__ h,
                                         const float* __restrict__ Wout,
                                         const float* __restrict__ bout,
                                         const float* __restrict__ ub,
                                         int bid, int tid, char* smemRaw) {
  double* sd    = reinterpret_cast<double*>(smemRaw);        // 256*8 (rescore)
  int*    pre   = reinterpret_cast<int*>(smemRaw + 2048);    // 256*4 (rare scan)
  int*    candV = reinterpret_cast<int*>(smemRaw + 3072);    // 64*4
  float*  swv   = reinterpret_cast<float*>(smemRaw + 3328);  // 4
  int*    swi   = reinterpret_cast<int*>(smemRaw + 3344);    // 4
  int*    sct   = reinterpret_cast<int*>(smemRaw + 3360);    // 4
  double* bestS = reinterpret_cast<double*>(smemRaw + 3376); // 8
  int*    bestV = reinterpret_cast<int*>(smemRaw + 3384);    // 4
  const int lane = tid & 63, wv = tid >> 6;
  const float* l0 = loP + (size_t)bid * V_;
  float sloc[16];
  float best = -1e30f; int bi = 0x7fffffff;
#pragma unroll
  for (int i = 0; i < 16; ++i) {
    int v = tid + 256 * i;
    float s = l0[v] + bout[v] - logf(-logf(ub[v]));
    sloc[i] = s;
    if (s > best) { best = s; bi = v; }
  }
#pragma unroll
  for (int off = 1; off < 64; off <<= 1) {
    float ov = __shfl_xor(best, off, 64);
    int   oi = __shfl_xor(bi,  off, 64);
    if (ov > best || (ov == best && oi < bi)) { best = ov; bi = oi; }
  }
  if (lane == 0) { swv[wv] = best; swi[wv] = bi; }
  __syncthreads();
  float smax = swv[0]; int amax = swi[0];
#pragma unroll
  for (int w = 1; w < 4; ++w) {
    float ov = swv[w]; int oi = swi[w];
    if (ov > smax || (ov == smax && oi < amax)) { smax = ov; amax = oi; }
  }
  int c = 0;
#pragma unroll
  for (int i = 0; i < 16; ++i) if (sloc[i] >= smax - MARGIN_) ++c;
  int csum = c;
#pragma unroll
  for (int off = 1; off < 64; off <<= 1) csum += __shfl_xor(csum, off, 64);
  if (lane == 0) sct[wv] = csum;
  __syncthreads();
  int tot = sct[0] + sct[1] + sct[2] + sct[3];

  int tok;
  if (tot == 1) {
    tok = amax;                                   // screen error << margin
  } else if (tot <= CCAP_) {
    int lv[16];
    int cc = 0;
#pragma unroll
    for (int i = 0; i < 16; ++i)
      if (sloc[i] >= smax - MARGIN_) { if (cc < 16) lv[cc] = tid + 256 * i; ++cc; }
    pre[tid] = cc;
    __syncthreads();
    for (int off = 1; off < 256; off <<= 1) {
      int vv = (tid >= off) ? pre[tid - off] : 0;
      __syncthreads();
      pre[tid] += vv;
      __syncthreads();
    }
    int base = pre[tid] - cc;
    for (int q = 0; q < cc; ++q) candV[base + q] = lv[q];
    if (tid == 0) { *bestS = -1e300; *bestV = 0x7fffffff; }
    __syncthreads();
    const float* hb = h + (size_t)bid * H_;
    for (int ci = 0; ci < tot; ++ci) {
      int v = candV[ci];
      const float* wr = Wout + (size_t)v * H_;
      double p = (double)hb[tid] * (double)wr[tid]
               + (double)hb[tid + 256] * (double)wr[tid + 256];
#pragma unroll
      for (int off = 1; off < 64; off <<= 1) p += __shfl_xor(p, off, 64);
      if (lane == 0) sd[wv] = p;
      __syncthreads();
      if (tid == 0) {
        double s = sd[0] + sd[1] + sd[2] + sd[3]
                 + (double)bout[v] - log(-log((double)ub[v]));
        if (s > *bestS || (s == *bestS && v < *bestV)) { *bestS = s; *bestV = v; }
      }
      __syncthreads();
    }
    tok = *bestV;
  } else {
    const float* hb = h + (size_t)bid * H_;
    double dbest = -1e300; int dbi = 0x7fffffff;
    for (int i = 0; i < 16; ++i) {
      int v = tid + 256 * i;
      const float* wr = Wout + (size_t)v * H_;
      double dot = 0.0;
      for (int k = 0; k < H_; ++k) dot = fma((double)hb[k], (double)wr[k], dot);
      double s = dot + (double)bout[v] - log(-log((double)ub[v]));
      if (s > dbest) { dbest = s; dbi = v; }
    }
#pragma unroll
    for (int off = 1; off < 64; off <<= 1) {
      double od = __shfl_xor(dbest, off, 64);
      int    oi = __shfl_xor(dbi,  off, 64);
      if (od > dbest || (od == dbest && oi < dbi)) { dbest = od; dbi = oi; }
    }
    if (lane == 0) { sd[wv] = dbest; pre[wv] = dbi; }
    __syncthreads();
    double bs = sd[0]; int bv = pre[0];
#pragma unroll
    for (int w = 1; w < 4; ++w) {
      if (sd[w] > bs || (sd[w] == bs && pre[w] < bv)) { bs = sd[w]; bv = pre[w]; }
    }
    tok = bv;
  }
  return tok;
}

// ===== K0: standalone gates (initial step, tok = SOS); 4 partials =====
__global__ __launch_bounds__(256) void gates_init(const float* __restrict__ ghP,
                                                  const float* __restrict__ giP,
                                                  const float* __restrict__ bih,
                                                  const float* __restrict__ bhh,
                                                  float* __restrict__ h,
                                                  __hip_bfloat16* __restrict__ hB) {
  const int bid = blockIdx.x, tid = threadIdx.x;
  const float* g0 = giP + (size_t)1 * 1536;
  size_t base = (size_t)bid * 1536;
#pragma unroll
  for (int c = 0; c < 2; ++c) {
    int j = c * 256 + tid;
    int idx = bid * 512 + j;
    double gr = (double)bhh[j], gz = (double)bhh[512 + j], gn = (double)bhh[1024 + j];
#pragma unroll
    for (int s = 0; s < 4; ++s) {
      const float* p = ghP + (size_t)s * 786432 + base;
      gr += (double)p[j]; gz += (double)p[512 + j]; gn += (double)p[1024 + j];
    }
    float ir  = g0[j]        + bih[j];
    float iz  = g0[512 + j]  + bih[512 + j];
    float inn = g0[1024 + j] + bih[1024 + j];
    float r = 1.f / (1.f + expf(-(ir + (float)gr)));
    float z = 1.f / (1.f + expf(-(iz + (float)gz)));
    float n = tanhf(inn + r * (float)gn);
    float hn = (1.f - z) * n + z * h[idx];
    h[idx] = hn;
    hB[idx] = __float2bfloat16(hn);
  }
}

// ===== K1: gh GEMM split-K=4 (blocks 0..383) + screen (384..895) =====
__global__ __launch_bounds__(256) void fusedA(const float* __restrict__ h,
                                              const float* __restrict__ Whh,
                                              const __hip_bfloat16* __restrict__ hB,
                                              const __hip_bfloat16* __restrict__ WoutB,
                                              float* __restrict__ ghP,
                                              float* __restrict__ loP,
                                              int doGemm) {
  __shared__ __align__(16) char smemRaw[12672];
  const int bid = blockIdx.x, tid = threadIdx.x;
  if (bid < 384) {
    if (doGemm) {
      int bx = bid % 24, by = (bid / 24) & 3, bz = bid / 96;
      gemm64_body(h, Whh, ghP, 1536, 512, 128, bx, by, bz, 4, tid, smemRaw);
    }
  } else {
    screen_body(hB, WoutB, loP, bid - 384, tid);
  }
}

// ===== K2: hoisted ghP sums (4 partials) -> pick tok(t) -> gates(t+1) =====
__global__ __launch_bounds__(256) void fusedB(const float* __restrict__ loP,
                                              float* __restrict__ h,
                                              const float* __restrict__ Wout,
                                              const float* __restrict__ bout,
                                              const float* __restrict__ u,   // step slice
                                              const float* __restrict__ ghP,
                                              const float* __restrict__ giP,
                                              const float* __restrict__ bih,
                                              const float* __restrict__ bhh,
                                              __hip_bfloat16* __restrict__ hB,
                                              int* __restrict__ toks,
                                              int t, int doGates) {
  __shared__ __align__(16) char smemRaw[5440];
  const int bid = blockIdx.x, tid = threadIdx.x;
  const int j0 = tid, j1 = 256 + tid;
  double gr0 = (double)bhh[j0], gz0 = (double)bhh[512 + j0], gn0 = (double)bhh[1024 + j0];
  double gr1 = (double)bhh[j1], gz1 = (double)bhh[512 + j1], gn1 = (double)bhh[1024 + j1];
  if (doGates) {
    size_t base = (size_t)bid * 1536;
#pragma unroll
    for (int s = 0; s < 4; ++s) {
      const float* p = ghP + (size_t)s * 786432 + base;
      gr0 += (double)p[j0]; gz0 += (double)p[512 + j0]; gn0 += (double)p[1024 + j0];
      gr1 += (double)p[j1]; gz1 += (double)p[512 + j1]; gn1 += (double)p[1024 + j1];
    }
  }
  const float* ub = u + (size_t)bid * V_;
  int tok = pick_body(loP, h, Wout, bout, ub, bid, tid, smemRaw);
  if (tid == 0) toks[t * B_ + bid] = tok;
  if (doGates) {
    const float* g0 = giP + (size_t)tok * 1536;
    {
      int idx = bid * 512 + j0;
      float ir  = g0[j0]        + bih[j0];
      float iz  = g0[512 + j0]  + bih[512 + j0];
      float inn = g0[1024 + j0] + bih[1024 + j0];
      float r = 1.f / (1.f + expf(-(ir + (float)gr0)));
      float z = 1.f / (1.f + expf(-(iz + (float)gz0)));
      float n = tanhf(inn + r * (float)gn0);
      float hn = (1.f - z) * n + z * h[idx];
      h[idx] = hn;
      hB[idx] = __float2bfloat16(hn);
    }
    {
      int idx = bid * 512 + j1;
      float ir  = g0[j1]        + bih[j1];
      float iz  = g0[512 + j1]  + bih[512 + j1];
      float inn = g0[1024 + j1] + bih[1024 + j1];
      float r = 1.f / (1.f + expf(-(ir + (float)gr1)));
      float z = 1.f / (1.f + expf(-(iz + (float)gz1)));
      float n = tanhf(inn + r * (float)gn1);
      float hn = (1.f - z) * n + z * h[idx];
      h[idx] = hn;
      hB[idx] = __float2bfloat16(hn);
    }
  }
}

// ============== final: zero + one-hot scatter + SOS/EOS, fp32 ==============
__global__ __launch_bounds__(256) void kfinal32(float* __restrict__ out,
                                                const int* __restrict__ toks) {
  size_t c = (size_t)blockIdx.x * 256 + threadIdx.x;
  size_t e0 = c * 4;
  int v0 = (int)(e0 & (size_t)(V_ - 1));
  size_t row = e0 >> 12;
  int p = (int)(row % L_);
  int b = (int)(row / L_);
  int tok;
  if (p == 0)           tok = 1;
  else if (p == L_ - 1) tok = 2;
  else                  tok = toks[(p - 1) * B_ + b];
  float4 val = make_float4(0.f, 0.f, 0.f, 0.f);
  int d = tok - v0;
  if (d >= 0 && d < 4) {
    if (d == 0) val.x = 1.f; else if (d == 1) val.y = 1.f;
    else if (d == 2) val.z = 1.f; else val.w = 1.f;
  }
  reinterpret_cast<float4*>(out)[c] = val;
}

// ---------------- environment markers ----------------
__global__ void kmark_ws(float* out) {
  if (threadIdx.x == 0) out[0] = 16.0f;
}
__global__ void kmark_resolver(float* out) {
  if (threadIdx.x == 0) out[2] = 11.0f;
}

// ================================ launch ================================
extern "C" void kernel_launch(void* const* d_in, const int* in_sizes, int n_in,
                              void* d_out, int out_size, void* d_ws, size_t ws_size,
                              hipStream_t stream) {
  static const int EXPECT[12] = {262144, 262144, 524288, 512, 393216, 786432,
                                 1536, 1536, 2097152, 4096, 1048576, 37748736};
  const float* R[12];
  bool resolved = (n_in == 12);
  if (resolved) {
    bool used[12] = {};
    for (int i = 0; i < 12; ++i) {
      int f = -1;
      for (int j = 0; j < 12; ++j)
        if (!used[j] && in_sizes[j] == EXPECT[i]) { f = j; break; }
      if (f < 0) { resolved = false; break; }
      used[f] = true;
      R[i] = (const float*)d_in[f];
    }
  }
  if (!resolved)
    for (int i = 0; i < 12 && i < n_in; ++i) R[i] = (const float*)d_in[i];

  const float *pa = R[0], *pb = R[1], *Winit = R[2], *binit = R[3],
              *Wih = R[4], *Whh = R[5], *bih = R[6], *bhh = R[7],
              *Wout = R[8], *bout = R[9], *emb = R[10], *ug = R[11];
  float* out = (float*)d_out;

  const size_t TOK_BYTES = (size_t)T_ * B_ * sizeof(int);   // 36864
  if (ws_size < TOK_BYTES) { kmark_ws<<<1, 64, 0, stream>>>(out); return; }
  int* toks = (int*)d_ws;

  // scratch: h | giP | ghP(4 chunks; aliases cat+h0P pre-loop) | loP | hB | WoutB
  const size_t SC_FLOATS = 16121856;
  float* sc;
  if (ws_size >= 40960 + SC_FLOATS * sizeof(float)) {
    sc = (float*)((char*)d_ws + 40960);
  } else {
    sc = (float*)d_out;   // head of 167.8 MB out; kfinal32 rebuilds last
  }
  float* h    = sc;                                   // 262,144
  float* giP  = sc + 262144;                          // 6,291,456 (4096x1536)
  float* ghP  = sc + 6553600;                         // 3,145,728 used (4 x 512x1536)
  float* loP  = sc + 12845056;                        // 2,097,152 (512x4096)
  __hip_bfloat16* hB    = (__hip_bfloat16*)(sc + 14942208);   // 262,144 bf16
  __hip_bfloat16* WoutB = (__hip_bfloat16*)(sc + 15073280);   // 2,097,152 bf16
  float* cat  = ghP;                                  // pre-loop only
  float* h0P  = ghP + 524288;                         // 8 x 262,144 (pre-loop only)

  // ---- setup ----
  kprep32<<<2560, 256, 0, stream>>>(pa, pb, Wout, cat, WoutB);
  setupGemms<<<1024, 256, 0, stream>>>(cat, Winit, h0P, emb, Wih, giP);
  reduceH0<<<1024, 256, 0, stream>>>(h0P, binit, h, hB);
  // gh(h_0) split-K=4, then gates(SOS) -> h_1
  ghK<<<384, 256, 0, stream>>>(h, Whh, ghP);
  gates_init<<<512, 256, 0, stream>>>(ghP, giP, bih, bhh, h, hB);

  // ---- decode loop: 2 launches per step ----
  for (int t = 0; t < T_; ++t) {
    const float* uslice = ug + (size_t)t * B_ * V_;
    int notLast = (t < T_ - 1) ? 1 : 0;
    // gh(h_{t+1}) -> ghP (blocks 0..383); screen(h_{t+1}) -> loP_t (384..895)
    fusedA<<<896, 256, 0, stream>>>(h, Whh, hB, WoutB, ghP, loP, notLast);
    // hoisted ghP sums ; pick tok_t ; gates -> h_{t+2}
    fusedB<<<512, 256, 0, stream>>>(loP, h, Wout, bout, uslice, ghP, giP,
                                    bih, bhh, hB, toks, t, notLast);
  }

  // ---- assemble fp32 output ----
  kfinal32<<<40960, 256, 0, stream>>>(out, toks);
  if (!resolved) kmark_resolver<<<1, 64, 0, stream>>>(out);
}